// Round 7
// baseline (227.737 us; speedup 1.0000x reference)
//
#include <hip/hip_runtime.h>
#include <hip/hip_bf16.h>

typedef unsigned short u16;
typedef __attribute__((ext_vector_type(4))) float f32x4;
typedef __attribute__((ext_vector_type(8))) short bf16x8;

#define SEQ 2048
#define DM 1024
#define DKK 64
#define NH 16
#define DFF 2048
#define TOK 4096

#define AS1 __attribute__((address_space(1)))
#define AS3 __attribute__((address_space(3)))

#define MFMA16(a, b, c) __builtin_amdgcn_mfma_f32_16x16x32_bf16((a), (b), (c), 0, 0, 0)

__device__ __forceinline__ u16 f2b(float f) {
  unsigned u = __float_as_uint(f);
  u = u + 0x7fffu + ((u >> 16) & 1u);
  return (u16)(u >> 16);
}

__device__ __forceinline__ unsigned cvtpk(float lo, float hi) {
  unsigned r;
  asm("v_cvt_pk_bf16_f32 %0, %1, %2" : "=v"(r) : "v"(lo), "v"(hi));
  return r;
}

__device__ __forceinline__ void gload_lds16(const u16* g, u16* l) {
  __builtin_amdgcn_global_load_lds((AS1 unsigned*)(size_t)g, (AS3 unsigned*)l, 16, 0, 0);
}

// ---------------- batched weight transpose fp32 [K,N] -> bf16 [N,K] ----------------
__global__ __launch_bounds__(256)
void transpose_all(const float* __restrict__ Wq, const float* __restrict__ Wk,
                   const float* __restrict__ Wv, const float* __restrict__ Wo,
                   const float* __restrict__ W1, const float* __restrict__ W2,
                   u16* __restrict__ Wqkt, u16* __restrict__ Wvt, u16* __restrict__ Wot,
                   u16* __restrict__ W1t, u16* __restrict__ W2t) {
  const int bid = blockIdx.x;
  const float* src;
  u16* dst;
  int K, N, lb;
  if (bid < 1024)      { src = Wq; dst = Wqkt;                 K = 1024; N = 1024; lb = bid; }
  else if (bid < 2048) { src = Wk; dst = Wqkt + (1 << 20);     K = 1024; N = 1024; lb = bid - 1024; }
  else if (bid < 3072) { src = Wv; dst = Wvt;                  K = 1024; N = 1024; lb = bid - 2048; }
  else if (bid < 4096) { src = Wo; dst = Wot;                  K = 1024; N = 1024; lb = bid - 3072; }
  else if (bid < 6144) { src = W1; dst = W1t;                  K = 1024; N = 2048; lb = bid - 4096; }
  else                 { src = W2; dst = W2t;                  K = 2048; N = 1024; lb = bid - 6144; }
  const int nx = N / 32;
  const int n0 = (lb % nx) * 32, k0 = (lb / nx) * 32;
  __shared__ float t[32][33];
  const int tx = threadIdx.x, ty = threadIdx.y;
#pragma unroll
  for (int i = 0; i < 4; i++) {
    int k = ty + i * 8;
    t[k][tx] = src[(size_t)(k0 + k) * N + n0 + tx];
  }
  __syncthreads();
#pragma unroll
  for (int i = 0; i < 4; i++) {
    int n = ty + i * 8;
    dst[(size_t)(n0 + n) * K + k0 + tx] = f2b(t[tx][n]);
  }
}

// ---------------- LayerNorm ----------------
__global__ __launch_bounds__(256)
void ln_kernel(const float* __restrict__ x, const float* __restrict__ alpha,
               const float* __restrict__ beta, u16* __restrict__ out) {
  const int row = blockIdx.x;
  const float4 v = ((const float4*)(x + (size_t)row * DM))[threadIdx.x];
  float s = v.x + v.y + v.z + v.w;
  float q = v.x * v.x + v.y * v.y + v.z * v.z + v.w * v.w;
#pragma unroll
  for (int off = 1; off < 64; off <<= 1) {
    s += __shfl_xor(s, off);
    q += __shfl_xor(q, off);
  }
  __shared__ float ss[4], qq[4];
  const int wid = threadIdx.x >> 6;
  if ((threadIdx.x & 63) == 0) { ss[wid] = s; qq[wid] = q; }
  __syncthreads();
  s = ss[0] + ss[1] + ss[2] + ss[3];
  q = qq[0] + qq[1] + qq[2] + qq[3];
  const float mean = s * (1.f / DM);
  float var = (q - (float)DM * mean * mean) * (1.f / (DM - 1));
  var = fmaxf(var, 0.f);
  const float inv = 1.f / (sqrtf(var) + 1e-6f);
  const float4 a4 = ((const float4*)alpha)[threadIdx.x];
  const float4 b4 = ((const float4*)beta)[threadIdx.x];
  ushort4 o;
  o.x = f2b((v.x - mean) * inv * a4.x + b4.x);
  o.y = f2b((v.y - mean) * inv * a4.y + b4.y);
  o.z = f2b((v.z - mean) * inv * a4.z + b4.z);
  o.w = f2b((v.w - mean) * inv * a4.w + b4.w);
  ((ushort4*)(out + (size_t)row * DM))[threadIdx.x] = o;
}

// ---------------- GEMM: C[M,N] = A[M,K](bf16,row) @ Bt[N,K](bf16,row)^T ----------------
// 1-D grid + bijective XCD swizzle (grid%8==0); triple-buffered LDS, counted vmcnt.
template <int MODE, int BM, int BN>
__global__ __launch_bounds__(256, 4)
void gemm_bt(const u16* __restrict__ A, const u16* __restrict__ Bt,
             int M, int N, int K,
             const float* __restrict__ bias, const float* __restrict__ res,
             void* __restrict__ outp, float oscale, int nm) {
  constexpr int AccM = BM / 32;
  constexpr int AccN = BN / 32;
  constexpr int L = (BM == 128 ? 2 : 1) + (BN == 128 ? 2 : 1);
  __shared__ alignas(16) u16 As[3][BM * 32];
  __shared__ alignas(16) u16 Bs[3][BN * 32];
  const int nwg = gridDim.x;
  const int cpx = nwg >> 3;
  const int wg = (blockIdx.x & 7) * cpx + (blockIdx.x >> 3);
  const int bm = (wg % nm) * BM, bn = (wg / nm) * BN;
  const int tid = threadIdx.x;
  const int lane = tid & 63, w = tid >> 6;
  const int wm = (w >> 1) * (BM / 2), wn = (w & 1) * (BN / 2);
  const int r = lane & 15, g = lane >> 4;
  const int srow = tid >> 2, skk = (tid & 3) * 8;

  f32x4 acc[AccM][AccN];
#pragma unroll
  for (int i = 0; i < AccM; i++)
#pragma unroll
    for (int j = 0; j < AccN; j++) acc[i][j] = (f32x4){0.f, 0.f, 0.f, 0.f};

  const u16* aP = A + (size_t)(bm + srow) * K + skk;
  const u16* bP = Bt + (size_t)(bn + srow) * K + skk;

  auto stage = [&](int kt, int buf) {
    gload_lds16(aP + kt, &As[buf][0] + w * 512);
    if (BM == 128) gload_lds16(aP + (size_t)64 * K + kt, &As[buf][0] + w * 512 + 2048);
    gload_lds16(bP + kt, &Bs[buf][0] + w * 512);
    if (BN == 128) gload_lds16(bP + (size_t)64 * K + kt, &Bs[buf][0] + w * 512 + 2048);
  };
  auto waitL = [&]() {
    if constexpr (L == 4) asm volatile("s_waitcnt vmcnt(4) lgkmcnt(0)" ::: "memory");
    else if constexpr (L == 3) asm volatile("s_waitcnt vmcnt(3) lgkmcnt(0)" ::: "memory");
    else asm volatile("s_waitcnt vmcnt(2) lgkmcnt(0)" ::: "memory");
  };
  auto compute = [&](int buf) {
    bf16x8 af[AccM], bfr[AccN];
#pragma unroll
    for (int i = 0; i < AccM; i++) af[i] = *(const bf16x8*)(&As[buf][(wm + i * 16 + r) * 32 + g * 8]);
#pragma unroll
    for (int j = 0; j < AccN; j++) bfr[j] = *(const bf16x8*)(&Bs[buf][(wn + j * 16 + r) * 32 + g * 8]);
#pragma unroll
    for (int i = 0; i < AccM; i++)
#pragma unroll
      for (int j = 0; j < AccN; j++) acc[i][j] = MFMA16(af[i], bfr[j], acc[i][j]);
  };

  const int NKT = K / 32;
  stage(0, 0);
  stage(32, 1);
  waitL();
  __builtin_amdgcn_s_barrier();
  __builtin_amdgcn_sched_barrier(0);
  for (int it = 0; it < NKT - 2; ++it) {
    stage((it + 2) * 32, (it + 2) % 3);
    compute(it % 3);
    waitL();
    __builtin_amdgcn_s_barrier();
    __builtin_amdgcn_sched_barrier(0);
  }
  compute((NKT - 2) % 3);
  asm volatile("s_waitcnt vmcnt(0) lgkmcnt(0)" ::: "memory");
  __builtin_amdgcn_s_barrier();
  __builtin_amdgcn_sched_barrier(0);
  compute((NKT - 1) % 3);

#pragma unroll
  for (int i = 0; i < AccM; i++)
#pragma unroll
    for (int j = 0; j < AccN; j++)
#pragma unroll
      for (int t = 0; t < 4; t++) {
        const int mg = bm + wm + i * 16 + g * 4 + t;
        const int ng = bn + wn + j * 16 + r;
        const float v = acc[i][j][t];
        if (MODE == 0) {  // fused QK
          const int which = ng >> 10, col = ng & 1023;
          const int bb = mg >> 11, ssx = mg & 2047, hh = col >> 6, dd = col & 63;
          const float sc = which ? 1.f : oscale;
          ((u16*)outp)[(size_t)which * (TOK * (size_t)DM) +
                       ((size_t)(bb * NH + hh) * SEQ + ssx) * DKK + dd] = f2b(v * sc);
        } else if (MODE == 1) {
          const int hh = mg >> 6, dd = mg & 63, bb = ng >> 11, ssx = ng & 2047;
          ((u16*)outp)[((size_t)(bb * NH + hh) * DKK + dd) * SEQ + ssx] = f2b(v);
        } else if (MODE == 2) {
          ((float*)outp)[(size_t)mg * N + ng] = res[(size_t)mg * N + ng] + v + bias[ng];
        } else {
          const float hv = v + bias[ng];
          ((u16*)outp)[(size_t)mg * N + ng] = f2b(hv > 0.f ? hv : 0.f);
        }
      }
}

// ---------------- flash attention: wave-split-S, barrier-free main loop ----------------
// Each wave owns a 512-wide k-chunk, processes all 64 q-rows of the block.
// Wave-private double-buffered LDS K/V tiles (KVBLK=32), counted vmcnt(8).
// No-max exp2 softmax -> cross-wave merge is a pure sum of (o, l) at the end.
__global__ __launch_bounds__(256, 2)
void attn_kernel(const u16* __restrict__ Q, const u16* __restrict__ Kb,
                 const u16* __restrict__ Vt, const float* __restrict__ mask,
                 u16* __restrict__ outc) {
  const int bid = blockIdx.x;
  const int bh = (bid & 7) * 4 + ((bid >> 3) & 3);  // 4 heads per XCD
  const int qt = bid >> 5;
  const int b = bh >> 4, h = bh & 15;
  const int tid = threadIdx.x, lane = tid & 63, w = tid >> 6;
  const int r = lane & 15, g = lane >> 4;
  const int qbase = qt * 64;
  const u16* Qp = Q + ((size_t)bh * SEQ + qbase) * DKK;
  const u16* Kp = Kb + (size_t)bh * SEQ * DKK;
  const u16* Vp = Vt + (size_t)bh * DKK * SEQ;
  const int wk0 = w * 512;  // this wave's k-chunk
  const float* mk = mask + b * SEQ + wk0;

  // Q B-frags (col q=r, contraction dk) for the block's 4 q-fragments
  bf16x8 bq0[4], bq1[4];
#pragma unroll
  for (int qf = 0; qf < 4; qf++) {
    bq0[qf] = *(const bf16x8*)(Qp + (size_t)(qf * 16 + r) * DKK + g * 8);
    bq1[qf] = *(const bf16x8*)(Qp + (size_t)(qf * 16 + r) * DKK + 32 + g * 8);
  }

  // per-wave LDS: [buf][K tile 32x64 | V tile 64x32]
  __shared__ __align__(16) char KV[4][2][8192];
  u16* const K0p = (u16*)&KV[w][0][0];
  u16* const K1p = (u16*)&KV[w][1][0];
  u16* const V0p = (u16*)&KV[w][0][4096];
  u16* const V1p = (u16*)&KV[w][1][4096];
  __shared__ float lrL[4][4][16];

  // staging source addresses (K pre-swizzled, V linear)
  const int srow8 = lane >> 3;
  const int sgr = (lane & 7) ^ srow8;
  const u16* kS = Kp + (size_t)(wk0 + srow8) * DKK + sgr * 8;
  const u16* vS = Vp + (size_t)(lane >> 2) * SEQ + wk0 + (lane & 3) * 8;

  f32x4 o[4][4];
#pragma unroll
  for (int i = 0; i < 4; i++)
#pragma unroll
    for (int j = 0; j < 4; j++) o[i][j] = (f32x4){0.f, 0.f, 0.f, 0.f};
  float lr[4] = {0.f, 0.f, 0.f, 0.f};
  const int keyr = r & 7;

  // prologue: stage tile 0 into buf0 (8 loads)
  gload_lds16(kS, K0p);
  gload_lds16(kS + (size_t)8 * DKK, K0p + 512);
  gload_lds16(kS + (size_t)16 * DKK, K0p + 1024);
  gload_lds16(kS + (size_t)24 * DKK, K0p + 1536);
  gload_lds16(vS, V0p);
  gload_lds16(vS + (size_t)16 * SEQ, V0p + 512);
  gload_lds16(vS + (size_t)32 * SEQ, V0p + 1024);
  gload_lds16(vS + (size_t)48 * SEQ, V0p + 1536);

#define ATILE(T, KP, VP, KPN, VPN, HASNEXT)                                           \
  do {                                                                                \
    const int kk = (T) * 32;                                                          \
    if (HASNEXT) {                                                                    \
      const int nk = kk + 32;                                                         \
      gload_lds16(kS + (size_t)nk * DKK, KPN);                                        \
      gload_lds16(kS + (size_t)(nk + 8) * DKK, KPN + 512);                            \
      gload_lds16(kS + (size_t)(nk + 16) * DKK, KPN + 1024);                          \
      gload_lds16(kS + (size_t)(nk + 24) * DKK, KPN + 1536);                          \
      gload_lds16(vS + nk, VPN);                                                      \
      gload_lds16(vS + (size_t)16 * SEQ + nk, VPN + 512);                             \
      gload_lds16(vS + (size_t)32 * SEQ + nk, VPN + 1024);                            \
      gload_lds16(vS + (size_t)48 * SEQ + nk, VPN + 1536);                            \
      asm volatile("s_waitcnt vmcnt(8)" ::: "memory");                                \
    } else {                                                                          \
      asm volatile("s_waitcnt vmcnt(0)" ::: "memory");                                \
    }                                                                                 \
    const bf16x8 ka0 = *(const bf16x8*)(KP + (size_t)(r)*64 + ((g ^ keyr) << 3));     \
    const bf16x8 ka1 = *(const bf16x8*)(KP + (size_t)(r)*64 + (((g + 4) ^ keyr) << 3));\
    const bf16x8 kb0 = *(const bf16x8*)(KP + (size_t)(16 + r) * 64 + ((g ^ keyr) << 3));\
    const bf16x8 kb1 = *(const bf16x8*)(KP + (size_t)(16 + r) * 64 + (((g + 4) ^ keyr) << 3));\
    f32x4 s0[4], s1[4];                                                               \
    __builtin_amdgcn_s_setprio(1);                                                    \
    _Pragma("unroll")                                                                 \
    for (int qf = 0; qf < 4; qf++) {                                                  \
      f32x4 z = (f32x4){0.f, 0.f, 0.f, 0.f};                                          \
      z = MFMA16(ka0, bq0[qf], z);                                                    \
      z = MFMA16(ka1, bq1[qf], z);                                                    \
      s0[qf] = z;                                                                     \
      f32x4 y = (f32x4){0.f, 0.f, 0.f, 0.f};                                          \
      y = MFMA16(kb0, bq0[qf], y);                                                    \
      y = MFMA16(kb1, bq1[qf], y);                                                    \
      s1[qf] = y;                                                                     \
    }                                                                                 \
    __builtin_amdgcn_s_setprio(0);                                                    \
    const float4 m0 = *(const float4*)(mk + kk + 4 * g);                              \
    const float4 m1 = *(const float4*)(mk + kk + 16 + 4 * g);                         \
    const int ones = (m0.x == 1.f) & (m0.y == 1.f) & (m0.z == 1.f) & (m0.w == 1.f) &  \
                     (m1.x == 1.f) & (m1.y == 1.f) & (m1.z == 1.f) & (m1.w == 1.f);   \
    const bool fastm = __all(ones);                                                   \
    bf16x8 pa[4];                                                                     \
    _Pragma("unroll")                                                                 \
    for (int qf = 0; qf < 4; qf++) {                                                  \
      float p[8];                                                                     \
      if (fastm) {                                                                    \
        p[0] = __builtin_amdgcn_exp2f(s0[qf][0]);                                     \
        p[1] = __builtin_amdgcn_exp2f(s0[qf][1]);                                     \
        p[2] = __builtin_amdgcn_exp2f(s0[qf][2]);                                     \
        p[3] = __builtin_amdgcn_exp2f(s0[qf][3]);                                     \
        p[4] = __builtin_amdgcn_exp2f(s1[qf][0]);                                     \
        p[5] = __builtin_amdgcn_exp2f(s1[qf][1]);                                     \
        p[6] = __builtin_amdgcn_exp2f(s1[qf][2]);                                     \
        p[7] = __builtin_amdgcn_exp2f(s1[qf][3]);                                     \
      } else {                                                                        \
        float pr;                                                                     \
        pr = s0[qf][0] * m0.x; p[0] = (pr == 0.f) ? 0.f : __builtin_amdgcn_exp2f(pr); \
        pr = s0[qf][1] * m0.y; p[1] = (pr == 0.f) ? 0.f : __builtin_amdgcn_exp2f(pr); \
        pr = s0[qf][2] * m0.z; p[2] = (pr == 0.f) ? 0.f : __builtin_amdgcn_exp2f(pr); \
        pr = s0[qf][3] * m0.w; p[3] = (pr == 0.f) ? 0.f : __builtin_amdgcn_exp2f(pr); \
        pr = s1[qf][0] * m1.x; p[4] = (pr == 0.f) ? 0.f : __builtin_amdgcn_exp2f(pr); \
        pr = s1[qf][1] * m1.y; p[5] = (pr == 0.f) ? 0.f : __builtin_amdgcn_exp2f(pr); \
        pr = s1[qf][2] * m1.z; p[6] = (pr == 0.f) ? 0.f : __builtin_amdgcn_exp2f(pr); \
        pr = s1[qf][3] * m1.w; p[7] = (pr == 0.f) ? 0.f : __builtin_amdgcn_exp2f(pr); \
      }                                                                               \
      float rs = ((p[0] + p[1]) + (p[2] + p[3])) + ((p[4] + p[5]) + (p[6] + p[7]));   \
      rs += __shfl_xor(rs, 16);                                                       \
      rs += __shfl_xor(rs, 32);                                                       \
      lr[qf] += rs;                                                                   \
      const unsigned w0 = cvtpk(p[0], p[1]), w1 = cvtpk(p[2], p[3]);                  \
      const unsigned w2 = cvtpk(p[4], p[5]), w3 = cvtpk(p[6], p[7]);                  \
      union { unsigned u[4]; bf16x8 v; } pu;                                          \
      _Pragma("unroll")                                                               \
      for (int c = 0; c < 4; c++) {                                                   \
        const int srcl = r + ((g & 1) * 2 + (c >> 1)) * 16;                           \
        const unsigned lo = __shfl((c & 1) ? w1 : w0, srcl);                          \
        const unsigned hi = __shfl((c & 1) ? w3 : w2, srcl);                          \
        pu.u[c] = (g < 2) ? lo : hi;                                                  \
      }                                                                               \
      pa[qf] = pu.v;                                                                  \
    }                                                                                 \
    __builtin_amdgcn_s_setprio(1);                                                    \
    _Pragma("unroll")                                                                 \
    for (int dc = 0; dc < 4; dc++) {                                                  \
      const bf16x8 bv = *(const bf16x8*)(VP + (size_t)(dc * 16 + r) * 32 + g * 8);    \
      _Pragma("unroll")                                                               \
      for (int qf = 0; qf < 4; qf++) o[qf][dc] = MFMA16(pa[qf], bv, o[qf][dc]);       \
    }                                                                                 \
    __builtin_amdgcn_s_setprio(0);                                                    \
  } while (0)

  for (int tt = 0; tt < 16; tt += 2) {
    ATILE(tt, K0p, V0p, K1p, V1p, true);
    ATILE(tt + 1, K1p, V1p, K0p, V0p, (tt < 14));
  }
#undef ATILE

  // ---- merge across waves: o_total = sum, l_total = sum ----
  float* mo = (float*)&KV[0][0][0];
  float* mw = mo + w * 4096;
#pragma unroll
  for (int qf = 0; qf < 4; qf++)
#pragma unroll
    for (int dc = 0; dc < 4; dc++)
      *(f32x4*)(mw + (size_t)((qf * 4 + dc) * 64 + lane) * 4) = o[qf][dc];
  if (lane < 16) {
#pragma unroll
    for (int qf = 0; qf < 4; qf++) lrL[w][qf][lane] = lr[qf];
  }
  __syncthreads();

  const int qf = w;  // each wave merges one q-fragment
  float lq[4];
#pragma unroll
  for (int t = 0; t < 4; t++)
    lq[t] = ((lrL[0][qf][4 * g + t] + lrL[1][qf][4 * g + t]) +
             (lrL[2][qf][4 * g + t] + lrL[3][qf][4 * g + t]));
#pragma unroll
  for (int dc = 0; dc < 4; dc++) {
    f32x4 a0 = *(const f32x4*)(mo + 0 * 4096 + (size_t)((qf * 4 + dc) * 64 + lane) * 4);
    f32x4 a1 = *(const f32x4*)(mo + 1 * 4096 + (size_t)((qf * 4 + dc) * 64 + lane) * 4);
    f32x4 a2 = *(const f32x4*)(mo + 2 * 4096 + (size_t)((qf * 4 + dc) * 64 + lane) * 4);
    f32x4 a3 = *(const f32x4*)(mo + 3 * 4096 + (size_t)((qf * 4 + dc) * 64 + lane) * 4);
#pragma unroll
    for (int t = 0; t < 4; t++) {
      const float val = ((a0[t] + a1[t]) + (a2[t] + a3[t])) / lq[t];
      const int srow_g = qbase + qf * 16 + g * 4 + t;
      outc[((size_t)(b * SEQ + srow_g)) * DM + h * DKK + dc * 16 + r] = f2b(val);
    }
  }
}

extern "C" void kernel_launch(void* const* d_in, const int* in_sizes, int n_in,
                              void* d_out, int out_size, void* d_ws, size_t ws_size,
                              hipStream_t stream) {
  const float* x    = (const float*)d_in[0];
  const float* mask = (const float*)d_in[1];
  const float* Wq   = (const float*)d_in[2];
  const float* Wk   = (const float*)d_in[3];
  const float* Wv   = (const float*)d_in[4];
  const float* Wo   = (const float*)d_in[5];
  const float* bo   = (const float*)d_in[6];
  const float* W1   = (const float*)d_in[7];
  const float* b1   = (const float*)d_in[8];
  const float* W2   = (const float*)d_in[9];
  const float* b2   = (const float*)d_in[10];
  const float* l1a  = (const float*)d_in[11];
  const float* l1b  = (const float*)d_in[12];
  const float* l2a  = (const float*)d_in[13];
  const float* l2b  = (const float*)d_in[14];

  char* wsb = (char*)d_ws;
  u16* Wqkt = (u16*)(wsb + (0ull << 20));
  u16* Wvt  = (u16*)(wsb + (4ull << 20));
  u16* Wot  = (u16*)(wsb + (6ull << 20));
  u16* W1t  = (u16*)(wsb + (8ull << 20));
  u16* W2t  = (u16*)(wsb + (12ull << 20));
  u16* x2   = (u16*)(wsb + (16ull << 20));
  u16* qkb  = (u16*)(wsb + (24ull << 20));
  u16* vtb  = (u16*)(wsb + (40ull << 20));
  float* x1 = (float*)(wsb + (48ull << 20));
  u16* concat = x2;
  u16* x2b = qkb;
  u16* hb  = (u16*)(wsb + (32ull << 20));

  const float qscale = 0.125f * 1.4426950408889634f;

  transpose_all<<<dim3(8192), dim3(32, 8), 0, stream>>>(Wq, Wk, Wv, Wo, W1, W2,
                                                        Wqkt, Wvt, Wot, W1t, W2t);

  ln_kernel<<<TOK, 256, 0, stream>>>(x, l1a, l1b, x2);

  gemm_bt<0, 64, 128><<<dim3(1024), 256, 0, stream>>>(
      x2, Wqkt, TOK, 2048, DM, nullptr, nullptr, qkb, qscale, 64);
  gemm_bt<1, 64, 64><<<dim3(1024), 256, 0, stream>>>(
      Wvt, x2, DM, TOK, DM, nullptr, nullptr, vtb, 1.0f, 16);

  attn_kernel<<<dim3(1024), 256, 0, stream>>>(qkb, qkb + (size_t)TOK * DM, vtb, mask, concat);

  gemm_bt<2, 64, 64><<<dim3(1024), 256, 0, stream>>>(
      concat, Wot, TOK, DM, DM, bo, x, x1, 1.0f, 64);

  ln_kernel<<<TOK, 256, 0, stream>>>(x1, l2a, l2b, x2b);

  gemm_bt<3, 64, 128><<<dim3(1024), 256, 0, stream>>>(
      x2b, W1t, TOK, DFF, DM, b1, nullptr, hb, 1.0f, 64);
  gemm_bt<2, 64, 64><<<dim3(1024), 256, 0, stream>>>(
      hb, W2t, TOK, DM, DFF, b2, x1, (float*)d_out, 1.0f, 64);
}